// Round 8
// baseline (241.688 us; speedup 1.0000x reference)
//
#include <hip/hip_runtime.h>
#include <hip/hip_bf16.h>

// TreeMLP fused kernel for MI355X (gfx950), round 8.
//
// pre_l = b1 + sum_{j>=l} x_blockj @ W1_blockj  -> reverse-order K-loop with
// snapshots; GEMM2 fused per snapshot. R8 = R7 + restored x LDS staging,
// SINGLE-buffered (R7 post-mortem: x-from-global thrashed L1 -> FETCH 45->147
// MB, main +47 us; single buffer fits barrier structure with no extra syncs):
//   stage x(7) -> barrier -> loop{ GEMM1(Xls) -> gelu -> Pbuf -> barrier ->
//   GEMM2(Pbuf) + stage x(j-1) into Xls + partial store -> barrier }
// LDS = 64 KB Pbuf + 16 KB Xls = 80 KB -> 2 blocks/CU; regs stay ~64 VGPR +
// 64 AGPR (no w2f hoist) -> 16 waves/CU.
//
// ws layout:
//   xt : fp16 [128 tg][64 kf][64 lane][8]      8 MB   (32x32 B-frag order)
//   w1t: fp16 [8 hq][64 kf][16 ht][64 lane][8] 8 MB   (32x32 A-frag order)
//   w2t: fp16 [128 kt2][8 rt][64 lane][8]      1 MB   (16x16 B-frag order)
//   partial: u32 [8 hq][64 tt][8 j][4 i][2 tp][4 q][8 rw][16 m16]  64 MB
// total 84,934,656 B.

typedef _Float16 half8 __attribute__((ext_vector_type(8)));
typedef _Float16 half4 __attribute__((ext_vector_type(4)));
typedef _Float16 half2v __attribute__((ext_vector_type(2)));
typedef float    f32x4  __attribute__((ext_vector_type(4)));
typedef float    f32x16 __attribute__((ext_vector_type(16)));

#define MFMA3216(A,B,C) __builtin_amdgcn_mfma_f32_32x32x16_f16(A, B, C, 0, 0, 0)
#define MFMA1632(A,B,C) __builtin_amdgcn_mfma_f32_16x16x32_f16(A, B, C, 0, 0, 0)

__device__ __forceinline__ float gelu_f(float x){
  // 0.5x(1+tanh(c(x+0.044715x^3))) == x * sigmoid(x*(2c + 2c*0.044715*x^2))
  // folded with log2(e) for direct exp2
  float t2 = x * fmaf(x*x, -0.10294324f, -2.30220842f);
  float e  = __builtin_amdgcn_exp2f(t2);
  return x * __builtin_amdgcn_rcpf(1.0f + e);
}

#define XROW 1028   // x-prep LDS row stride in halves (1024 + 4: 2-way free)

// ---- fused prep: cast fp32->fp16 into MFMA fragment lane order ----
__global__ void k_prep(const float* __restrict__ x, const float* __restrict__ w1,
                       const float* __restrict__ w2,
                       _Float16* __restrict__ xt, _Float16* __restrict__ w1t,
                       _Float16* __restrict__ w2t){
  __shared__ _Float16 Xs[32*XROW];                   // 65.8 KB (x-branch only)
  int bid = blockIdx.x;
  int t   = threadIdx.x;
  if (bid < 128){                                    // xt: 32x32 B-frags
    // phase 1: coalesced read of 32 tokens x 1024 cols -> padded LDS
    const float4* x4 = reinterpret_cast<const float4*>(x) + (size_t)bid*8192;
    #pragma unroll
    for (int i = 0; i < 32; ++i){
      float4 v = x4[i*256 + t];
      half4 h;
      h[0]=(_Float16)v.x; h[1]=(_Float16)v.y; h[2]=(_Float16)v.z; h[3]=(_Float16)v.w;
      *reinterpret_cast<half4*>(Xs + i*XROW + t*4) = h;
    }
    __syncthreads();
    // phase 2: emit 32x32 B-fragments (tgg = bid)
    #pragma unroll
    for (int f = 0; f < 16; ++f){
      int fragidx = f*256 + t;                       // [kf 64][lane 64]
      int lane = fragidx & 63, kf = fragidx >> 6;
      int tok32 = lane & 31;
      int k = kf*16 + (lane >> 5)*8;
      half8 v = *reinterpret_cast<const half8*>(Xs + tok32*XROW + k);
      *reinterpret_cast<half8*>(xt + ((size_t)bid*4096 + fragidx)*8) = v;
    }
  } else if (bid < 2176){                            // w1t: 32x32 A-frags
    int tid = (bid - 128)*256 + t;
    int lane = tid & 63;
    int ht   = (tid >> 6) & 15;
    int kf   = (tid >> 10) & 63;
    int hq   = tid >> 16;
    int n = hq*512 + ht*32 + (lane & 31);
    int k = kf*16 + (lane >> 5)*8;
    half8 v;
    #pragma unroll
    for (int jj = 0; jj < 8; ++jj) v[jj] = (_Float16)w1[(size_t)(k + jj)*4096 + n];
    *reinterpret_cast<half8*>(w1t + (size_t)tid*8) = v;
  } else {                                           // w2t: 16x16 B-frags
    int tid = (bid - 2176)*256 + t;
    int lane = tid & 63;
    int tile = tid >> 6;
    int ntr = tile & 7, kt2 = tile >> 3;
    int n = ntr*16 + (lane & 15);
    int k = kt2*32 + (lane >> 4)*8;
    half8 v;
    #pragma unroll
    for (int jj = 0; jj < 8; ++jj) v[jj] = (_Float16)w2[(size_t)(k + jj)*128 + n];
    *reinterpret_cast<half8*>(w2t + (size_t)tid*8) = v;
  }
}

__global__ void k_init_out(const float* __restrict__ b2, float* __restrict__ out){
  int i = blockIdx.x*256 + threadIdx.x;              // 1048576 float4s
  float4 bv = reinterpret_cast<const float4*>(b2)[i & 31];
  reinterpret_cast<float4*>(out)[i] = bv;
}

// ---- reduce: out = b2 + sum over 8 H-eighth fp16 partials ----
__global__ void k_reduce(const unsigned* __restrict__ part, const float* __restrict__ b2,
                         float* __restrict__ out){
  int tid = blockIdx.x*256 + threadIdx.x;            // 0..2097151
  int m16 = tid & 15;
  int rw  = (tid >> 4) & 7;
  int q   = (tid >> 7) & 3;
  int tp  = (tid >> 9) & 1;
  int i   = (tid >> 10) & 3;
  int j   = (tid >> 12) & 7;
  int tt  = tid >> 15;
  float s0 = 0.f, s1 = 0.f;
  #pragma unroll
  for (int hq = 0; hq < 8; ++hq){
    unsigned v = __builtin_nontemporal_load(part + (size_t)hq*2097152 + tid);
    half2v h = __builtin_bit_cast(half2v, v);
    s0 += (float)h[0];
    s1 += (float)h[1];
  }
  int r = rw*16 + m16;
  int tok0 = tt*64 + tp*32 + q*4 + i;                // tf = 2*tp
  float bb = b2[r];
  out[(size_t)tok0*1024 + j*128 + r]        = s0 + bb;
  out[(size_t)(tok0 + 16)*1024 + j*128 + r] = s1 + bb;   // tf = 2*tp+1
}

// ---- main fused kernel ----
// grid 512 x 512 thr (8 waves, 2 blocks/CU). block = (64 tok) x (H-8th 512).
// GEMM1 (32x32x16, transposed): wave w owns hcol-tiles (w*2, w*2+1) for both
// 32-token groups, x frags from single-buffered Xls (staged during prior I2).
// gelu -> P in 16x16 A-frag order -> barrier -> GEMM2 (16x16x32): wave =
// R-slice w, 4 token-tiles, K=512, w2 frags from L1 (jr-invariant addrs);
// stage x(j-1) + partial store in the same interval; barrier.
__global__ __launch_bounds__(512, 4) void k_treemlp(
    const _Float16* __restrict__ xt, const _Float16* __restrict__ w1t,
    const _Float16* __restrict__ w2t, const float* __restrict__ b1,
    unsigned* __restrict__ partial, float* __restrict__ out, int use_partial){
  int b    = blockIdx.x;
  int hq   = b & 7;                     // H-eighth == XCD slot
  int tt   = b >> 3;                    // token tile 0..63 (64 tokens)
  int t    = threadIdx.x;
  int w    = t >> 6;                    // wave 0..7
  int lane = t & 63;
  int t32 = lane & 31, q2 = lane >> 5;
  int m16 = lane & 15, q4 = lane >> 4;

  __shared__ _Float16 Pbuf[32768];      // 64 KB: [tf 4][kf 16][lane 64][8]
  __shared__ _Float16 Xls[8192];        // 16 KB: [tg 2][ks 8][lane 64][8]

  // GEMM1 suffix accumulators (C^T: rows=hcol, cols=tok), init with b1
  f32x16 acc1[2][2];                    // [hcol-tile hf][tok-group tg]
  #pragma unroll
  for (int hf = 0; hf < 2; ++hf){
    int base = hq*512 + (w*2 + hf)*32;
    #pragma unroll
    for (int g = 0; g < 4; ++g){
      float4 bv = *reinterpret_cast<const float4*>(b1 + base + 8*g + 4*q2);
      #pragma unroll
      for (int c = 0; c < 4; ++c){
        acc1[hf][0][g*4 + c] = ((const float*)&bv)[c];
        acc1[hf][1][g*4 + c] = ((const float*)&bv)[c];
      }
    }
  }

  // ---- x staging: level J -> Xls (16 KB, frag order, 2 b128/thread)
  #define STAGE_X(J) do {                                                   \
    int s0 = t, s1 = t + 512;                                               \
    half8 v0 = *reinterpret_cast<const half8*>(                             \
        xt + (size_t)((tt*2 + (s0 >> 9))*64 + (J)*8 + ((s0 >> 6) & 7))*512  \
           + (s0 & 63)*8);                                                  \
    half8 v1 = *reinterpret_cast<const half8*>(                             \
        xt + (size_t)((tt*2 + (s1 >> 9))*64 + (J)*8 + ((s1 >> 6) & 7))*512  \
           + (s1 & 63)*8);                                                  \
    *reinterpret_cast<half8*>(&Xls[s0*8]) = v0;                             \
    *reinterpret_cast<half8*>(&Xls[s1*8]) = v1;                             \
  } while (0)

  STAGE_X(7);
  __syncthreads();

  const _Float16* w1base = w1t + (size_t)hq*65536*8 + (size_t)(w*2)*512 + lane*8;
  const _Float16* w2base = w2t + (size_t)(hq*16*8 + w)*512 + lane*8; // + kf*4096

  #pragma unroll
  for (int jr = 0; jr < 8; ++jr){
    int j = 7 - jr;                      // reverse K-block order -> suffix sums

    // ---- I1: GEMM1 level j (8 k-steps of 16, x from Xls) ----
    #pragma unroll
    for (int s = 0; s < 8; ++s){
      int kf = j*8 + s;
      half8 a0 = *reinterpret_cast<const half8*>(w1base + (size_t)(kf*16    )*512);
      half8 a1 = *reinterpret_cast<const half8*>(w1base + (size_t)(kf*16 + 1)*512);
      half8 x0 = *reinterpret_cast<const half8*>(&Xls[((     s)*64 + lane)*8]);
      half8 x1 = *reinterpret_cast<const half8*>(&Xls[((8  + s)*64 + lane)*8]);
      acc1[0][0] = MFMA3216(a0, x0, acc1[0][0]);
      acc1[0][1] = MFMA3216(a0, x1, acc1[0][1]);
      acc1[1][0] = MFMA3216(a1, x0, acc1[1][0]);
      acc1[1][1] = MFMA3216(a1, x1, acc1[1][1]);
    }

    // gelu snapshot -> P (16x16 A-frag order; writes are half4 b64)
    #pragma unroll
    for (int hf = 0; hf < 2; ++hf){
      int kfp = w*2 + hf;
      #pragma unroll
      for (int tg = 0; tg < 2; ++tg){
        int tf = tg*2 + (t32 >> 4);
        #pragma unroll
        for (int g = 0; g < 4; ++g){
          half4 hv;
          #pragma unroll
          for (int c = 0; c < 4; ++c)
            hv[c] = (_Float16)gelu_f(acc1[hf][tg][g*4 + c]);
          *reinterpret_cast<half4*>(
              Pbuf + ((tf*16 + kfp)*64 + g*16 + (t32 & 15))*8 + 4*q2) = hv;
        }
      }
    }
    __syncthreads();   // Pbuf ready; all waves are past GEMM1 -> Xls reusable

    // ---- I2: GEMM2 level j (K=512) + stage x(j-1) + partial store ----
    if (jr < 7) STAGE_X(j - 1);

    f32x4 outJ[4];
    #pragma unroll
    for (int tf = 0; tf < 4; ++tf) outJ[tf] = f32x4{0.f, 0.f, 0.f, 0.f};

    #pragma unroll
    for (int kf = 0; kf < 16; ++kf){
      half8 wf = *reinterpret_cast<const half8*>(w2base + (size_t)kf*4096);
      #pragma unroll
      for (int tf = 0; tf < 4; ++tf){
        half8 a2 = *reinterpret_cast<const half8*>(
            Pbuf + ((tf*16 + kf)*64 + lane)*8);
        outJ[tf] = MFMA1632(a2, wf, outJ[tf]);
      }
    }

    if (use_partial){
      // u32 [hq][tt][j][i][tp][q][rw][m16]
      unsigned* pb = partial + (size_t)hq*2097152 + (size_t)tt*32768
                   + (size_t)j*4096 + q4*128 + w*16 + m16;
      #pragma unroll
      for (int i = 0; i < 4; ++i)
        #pragma unroll
        for (int tp = 0; tp < 2; ++tp){
          half2v p;
          p[0] = (_Float16)outJ[tp*2    ][i];
          p[1] = (_Float16)outJ[tp*2 + 1][i];
          __builtin_nontemporal_store(__builtin_bit_cast(unsigned, p),
                                      pb + (size_t)i*1024 + tp*512);
        }
    } else {
      #pragma unroll
      for (int tf = 0; tf < 4; ++tf)
        #pragma unroll
        for (int i = 0; i < 4; ++i){
          int tok = tt*64 + tf*16 + q4*4 + i;
          atomicAdd(out + (size_t)tok*1024 + j*128 + w*16 + m16, outJ[tf][i]);
        }
    }
    __syncthreads();   // publishes Xls(j-1); Pbuf free for next gelu
  }
  #undef STAGE_X
}

extern "C" void kernel_launch(void* const* d_in, const int* in_sizes, int n_in,
                              void* d_out, int out_size, void* d_ws, size_t ws_size,
                              hipStream_t stream){
  (void)in_sizes; (void)n_in; (void)out_size;
  const float* x  = (const float*)d_in[0];
  const float* W1 = (const float*)d_in[1];
  const float* b1 = (const float*)d_in[2];
  const float* W2 = (const float*)d_in[3];
  const float* b2 = (const float*)d_in[4];
  float* out = (float*)d_out;

  _Float16* xt  = (_Float16*)d_ws;
  _Float16* w1t = xt  + 4194304;
  _Float16* w2t = w1t + 4194304;
  unsigned* partial = (unsigned*)(w2t + 524288);   // 64 MB packed fp16
  const size_t need = (size_t)(4194304 + 4194304 + 524288)*2 + (size_t)16777216*4;
  int use_partial = (ws_size >= need) ? 1 : 0;

  hipLaunchKernelGGL(k_prep, dim3(2432), dim3(256), 0, stream, x, W1, W2, xt, w1t, w2t);
  if (!use_partial)
    hipLaunchKernelGGL(k_init_out, dim3(4096), dim3(256), 0, stream, b2, out);
  hipLaunchKernelGGL(k_treemlp, dim3(512), dim3(512), 0, stream,
                     xt, w1t, w2t, b1, partial, out, use_partial);
  if (use_partial)
    hipLaunchKernelGGL(k_reduce, dim3(8192), dim3(256), 0, stream, partial, b2, out);
}

// Round 9
// 216.340 us; speedup vs baseline: 1.1172x; 1.1172x over previous
//
#include <hip/hip_runtime.h>
#include <hip/hip_bf16.h>

// TreeMLP fused kernel for MI355X (gfx950), round 9.
//
// pre_l = b1 + sum_{j>=l} x_blockj @ W1_blockj  -> reverse-order K-loop with
// snapshots; GEMM2 fused per snapshot. R9: PRODUCER/CONSUMER wave split.
//  - 1024-thr blocks (16 waves, 1 block/CU, 4 waves/SIMD): waves 0-7 run
//    GEMM1 (32x32x16) + gelu + Pbuf writes; waves 8-15 run GEMM2 as
//    32x32x16 (2.4x denser than 16x16 per FLOP), cell = (tokhalf, Rtile),
//    K=512, w2 streamed from L2 (loads overlap producer MFMA on same SIMD)
//  - full dbuf: Pbuf 2x64KB + Xls 2x16KB = 160 KB -> ONE barrier per level
//    (9 pipelined intervals; was 16 barriers)
//  - partial stores = full 128B-line wave stores (R8 had 64B segments
//    needing cross-wave L2 merge -> 2x write amplification + RMW fetch)
//
// ws layout:
//   xt : fp16 [128 tg][64 kf][64 lane][8]      8 MB   (32x32 B-frag order)
//   w1t: fp16 [8 hq][64 kf][16 ht][64 lane][8] 8 MB   (32x32 A-frag order)
//   w2t: fp16 [8 hq][32 kf][4 rt][64 lane][8]  1 MB   (32x32 B-frag order)
//   partial: u32 [8 hq][64 tt][8 j][32 tc][128 r]     64 MB
// total 84,934,656 B.

typedef _Float16 half8 __attribute__((ext_vector_type(8)));
typedef _Float16 half4 __attribute__((ext_vector_type(4)));
typedef _Float16 half2v __attribute__((ext_vector_type(2)));
typedef float    f32x4  __attribute__((ext_vector_type(4)));
typedef float    f32x16 __attribute__((ext_vector_type(16)));

#define MFMA3216(A,B,C) __builtin_amdgcn_mfma_f32_32x32x16_f16(A, B, C, 0, 0, 0)

__device__ __forceinline__ float gelu_f(float x){
  // 0.5x(1+tanh(c(x+0.044715x^3))) == x * sigmoid(x*(2c + 2c*0.044715*x^2))
  // folded with log2(e) for direct exp2
  float t2 = x * fmaf(x*x, -0.10294324f, -2.30220842f);
  float e  = __builtin_amdgcn_exp2f(t2);
  return x * __builtin_amdgcn_rcpf(1.0f + e);
}

#define XROW 1028   // x-prep LDS row stride in halves (1024 + 4: 2-way free)

// ---- fused prep: cast fp32->fp16 into MFMA fragment lane order ----
__global__ void k_prep(const float* __restrict__ x, const float* __restrict__ w1,
                       const float* __restrict__ w2,
                       _Float16* __restrict__ xt, _Float16* __restrict__ w1t,
                       _Float16* __restrict__ w2t){
  __shared__ _Float16 Xs[32*XROW];                   // 65.8 KB (x-branch only)
  int bid = blockIdx.x;
  int t   = threadIdx.x;
  if (bid < 128){                                    // xt: 32x32 B-frags
    // phase 1: coalesced read of 32 tokens x 1024 cols -> padded LDS
    const float4* x4 = reinterpret_cast<const float4*>(x) + (size_t)bid*8192;
    #pragma unroll
    for (int i = 0; i < 32; ++i){
      float4 v = x4[i*256 + t];
      half4 h;
      h[0]=(_Float16)v.x; h[1]=(_Float16)v.y; h[2]=(_Float16)v.z; h[3]=(_Float16)v.w;
      *reinterpret_cast<half4*>(Xs + i*XROW + t*4) = h;
    }
    __syncthreads();
    // phase 2: emit 32x32 B-fragments (tgg = bid)
    #pragma unroll
    for (int f = 0; f < 16; ++f){
      int fragidx = f*256 + t;                       // [kf 64][lane 64]
      int lane = fragidx & 63, kf = fragidx >> 6;
      int tok32 = lane & 31;
      int k = kf*16 + (lane >> 5)*8;
      half8 v = *reinterpret_cast<const half8*>(Xs + tok32*XROW + k);
      *reinterpret_cast<half8*>(xt + ((size_t)bid*4096 + fragidx)*8) = v;
    }
  } else if (bid < 2176){                            // w1t: 32x32 A-frags
    int tid = (bid - 128)*256 + t;
    int lane = tid & 63;
    int ht   = (tid >> 6) & 15;
    int kf   = (tid >> 10) & 63;
    int hq   = tid >> 16;
    int n = hq*512 + ht*32 + (lane & 31);
    int k = kf*16 + (lane >> 5)*8;
    half8 v;
    #pragma unroll
    for (int jj = 0; jj < 8; ++jj) v[jj] = (_Float16)w1[(size_t)(k + jj)*4096 + n];
    *reinterpret_cast<half8*>(w1t + (size_t)tid*8) = v;
  } else {                                           // w2t: 32x32 B-frags
    int tid = (bid - 2176)*256 + t;                  // 65536 frag-lanes
    int lane = tid & 63;
    int rt   = (tid >> 6) & 3;
    int kf   = (tid >> 8) & 31;
    int hq   = tid >> 13;
    int n = rt*32 + (lane & 31);
    int k = hq*512 + kf*16 + (lane >> 5)*8;
    half8 v;
    #pragma unroll
    for (int jj = 0; jj < 8; ++jj) v[jj] = (_Float16)w2[(size_t)(k + jj)*128 + n];
    *reinterpret_cast<half8*>(w2t + (size_t)tid*8) = v;
  }
}

__global__ void k_init_out(const float* __restrict__ b2, float* __restrict__ out){
  int i = blockIdx.x*256 + threadIdx.x;              // 1048576 float4s
  float4 bv = reinterpret_cast<const float4*>(b2)[i & 31];
  reinterpret_cast<float4*>(out)[i] = bv;
}

// ---- reduce: out = b2 + sum over 8 H-eighth fp16 partials ----
// partial u32 layout: [hq][tt][j][tc 32][r 128]; u32 = {tok t, tok t+8} halves
// where t = (tc>>3)*16 + (tc&7).
__global__ void k_reduce(const unsigned* __restrict__ part, const float* __restrict__ b2,
                         float* __restrict__ out){
  int tid = blockIdx.x*256 + threadIdx.x;            // 0..2097151
  int r   = tid & 127;
  int tc  = (tid >> 7) & 31;
  int j   = (tid >> 12) & 7;
  int tt  = tid >> 15;
  float s0 = 0.f, s1 = 0.f;
  #pragma unroll
  for (int hq = 0; hq < 8; ++hq){
    unsigned v = __builtin_nontemporal_load(part + (size_t)hq*2097152 + tid);
    half2v h = __builtin_bit_cast(half2v, v);
    s0 += (float)h[0];
    s1 += (float)h[1];
  }
  int tka = tt*64 + (tc >> 3)*16 + (tc & 7);
  float bb = b2[r];
  out[(size_t)tka*1024 + j*128 + r]       = s0 + bb;
  out[(size_t)(tka+8)*1024 + j*128 + r]   = s1 + bb;
}

// ---- main fused kernel ----
// grid 512 x 1024 thr (16 waves, 1 block/CU). block = (64 tok) x (H-8th 512).
// Producers (w 0-7): GEMM1 32x32x16 (wave = 2 hcol-tiles x 2 tok-groups,
// acc1[2][2] f32x16 suffix accumulators) + gelu -> Pbuf[L&1]; also stage
// x(L-1) -> Xls[(L-1)&1]. Consumers (w 8-15): GEMM2 32x32x16, cell =
// (tokhalf th, Rtile rt), K=512 (32 kf), w2 frags streamed from L2;
// full-line partial stores. ONE barrier per interval, 9 intervals.
__global__ __launch_bounds__(1024, 4) void k_treemlp(
    const _Float16* __restrict__ xt, const _Float16* __restrict__ w1t,
    const _Float16* __restrict__ w2t, const float* __restrict__ b1,
    unsigned* __restrict__ partial, float* __restrict__ out, int use_partial){
  int b    = blockIdx.x;
  int hq   = b & 7;                     // H-eighth == XCD slot
  int tt   = b >> 3;                    // token tile 0..63 (64 tokens)
  int t    = threadIdx.x;
  int w    = t >> 6;                    // wave 0..15
  int lane = t & 63;
  int t32 = lane & 31, q2 = lane >> 5;

  __shared__ _Float16 Pbuf[2][32768];   // 2 x 64 KB: [th 2][kf 32][lane][8]
  __shared__ _Float16 Xls[2][8192];     // 2 x 16 KB: [tg 2][s 8][lane][8]

  // producer state: suffix accumulators (C^T: rows=hcol, cols=tok), b1-init
  f32x16 acc1[2][2];                    // [hcol-tile hf][tok-group tg]
  if (w < 8){
    #pragma unroll
    for (int hf = 0; hf < 2; ++hf){
      int base = hq*512 + (w*2 + hf)*32;
      #pragma unroll
      for (int g = 0; g < 4; ++g){
        float4 bv = *reinterpret_cast<const float4*>(b1 + base + 8*g + 4*q2);
        #pragma unroll
        for (int c = 0; c < 4; ++c){
          acc1[hf][0][g*4 + c] = ((const float*)&bv)[c];
          acc1[hf][1][g*4 + c] = ((const float*)&bv)[c];
        }
      }
    }
  }

  // initial stage: level 7 -> Xls[1] (all 1024 threads, one b128 each)
  {
    int lane_s = t & 63, s = (t >> 6) & 7, tgl = (t >> 9) & 1;
    half8 v = *reinterpret_cast<const half8*>(
        xt + (size_t)((tt*2 + tgl)*64 + 7*8 + s)*512 + lane_s*8);
    *reinterpret_cast<half8*>(&Xls[1][(size_t)t*8]) = v;
  }
  __syncthreads();

  const _Float16* w1base = w1t + (size_t)hq*524288 + (size_t)(w*2)*512 + lane*8;
  int wc = w - 8;
  int th = (wc >> 2) & 1, rt = wc & 3;  // consumer cell
  const _Float16* w2base = w2t + ((size_t)(hq*32)*4 + rt)*512 + lane*8; // + kf*2048

  #pragma unroll
  for (int k = 0; k < 9; ++k){
    if (w < 8){
      // ================= PRODUCER =================
      if (k <= 7){
        int L = 7 - k;                   // level being produced
        // stage x(L-1) for next interval (2 b128 per producer thread)
        if (L >= 1){
          #pragma unroll
          for (int c = 0; c < 2; ++c){
            int idx = c*512 + (w*64 + lane);
            int lane_s = idx & 63, s = (idx >> 6) & 7, tgl = idx >> 9;
            half8 v = *reinterpret_cast<const half8*>(
                xt + (size_t)((tt*2 + tgl)*64 + (L-1)*8 + s)*512 + lane_s*8);
            *reinterpret_cast<half8*>(&Xls[(L-1) & 1][(size_t)idx*8]) = v;
          }
        }
        // GEMM1 level L: 8 k-steps of 16
        const _Float16* xb = Xls[L & 1];
        #pragma unroll
        for (int s = 0; s < 8; ++s){
          int kfg = L*8 + s;
          half8 a0 = *reinterpret_cast<const half8*>(w1base + (size_t)(kfg*16    )*512);
          half8 a1 = *reinterpret_cast<const half8*>(w1base + (size_t)(kfg*16 + 1)*512);
          half8 x0 = *reinterpret_cast<const half8*>(&xb[(size_t)((    s)*64 + lane)*8]);
          half8 x1 = *reinterpret_cast<const half8*>(&xb[(size_t)((8 + s)*64 + lane)*8]);
          acc1[0][0] = MFMA3216(a0, x0, acc1[0][0]);
          acc1[0][1] = MFMA3216(a0, x1, acc1[0][1]);
          acc1[1][0] = MFMA3216(a1, x0, acc1[1][0]);
          acc1[1][1] = MFMA3216(a1, x1, acc1[1][1]);
        }
        // gelu -> Pbuf[L&1] in 32x32 A-frag order (half4 b64 writes)
        _Float16* pb = Pbuf[L & 1];
        #pragma unroll
        for (int hf = 0; hf < 2; ++hf)
          #pragma unroll
          for (int tg = 0; tg < 2; ++tg)
            #pragma unroll
            for (int g2 = 0; g2 < 4; ++g2){
              half4 hv;
              #pragma unroll
              for (int rr = 0; rr < 4; ++rr)
                hv[rr] = (_Float16)gelu_f(acc1[hf][tg][g2*4 + rr]);
              // h = (w*2+hf)*32 + rr + 8*g2 + 4*q2 ; tok = tg*32 + t32
              // dest frag: kf = (w*2+hf)*2 + (g2>>1), lane2 = t32 + 32*(g2&1)
              int kf = (w*2 + hf)*2 + (g2 >> 1);
              *reinterpret_cast<half4*>(
                  &pb[(size_t)((tg*32 + kf)*64 + t32 + 32*(g2 & 1))*8 + 4*q2]) = hv;
            }
      }
    } else {
      // ================= CONSUMER =================
      if (k >= 1){
        int Lc = 8 - k;                  // level being consumed
        const _Float16* pb = Pbuf[Lc & 1];
        f32x16 outJ;
        #pragma unroll
        for (int c = 0; c < 16; ++c) outJ[c] = 0.f;
        #pragma unroll
        for (int kf = 0; kf < 32; ++kf){
          half8 wf = *reinterpret_cast<const half8*>(w2base + (size_t)kf*2048);
          half8 pf = *reinterpret_cast<const half8*>(
              &pb[(size_t)((th*32 + kf)*64 + lane)*8]);
          outJ = MFMA3216(pf, wf, outJ);
        }
        if (use_partial){
          // full-line stores: u32[hq][tt][j][tc][r]
          unsigned* pbase = partial + (size_t)hq*2097152 + (size_t)tt*32768
                          + (size_t)Lc*4096;
          #pragma unroll
          for (int i = 0; i < 8; ++i){
            int gg = i >> 2, ii = i & 3;
            int lo = gg*8 + ii;
            half2v p;
            p[0] = (_Float16)outJ[lo];
            p[1] = (_Float16)outJ[lo + 4];
            int tc = (th*2 + gg)*8 + ii + 4*q2;
            __builtin_nontemporal_store(__builtin_bit_cast(unsigned, p),
                                        pbase + (size_t)tc*128 + rt*32 + t32);
          }
        } else {
          #pragma unroll
          for (int reg = 0; reg < 16; ++reg){
            int tok = tt*64 + th*32 + (reg & 3) + 8*(reg >> 2) + 4*q2;
            atomicAdd(out + (size_t)tok*1024 + Lc*128 + rt*32 + t32, outJ[reg]);
          }
        }
      }
    }
    __syncthreads();
  }
}

extern "C" void kernel_launch(void* const* d_in, const int* in_sizes, int n_in,
                              void* d_out, int out_size, void* d_ws, size_t ws_size,
                              hipStream_t stream){
  (void)in_sizes; (void)n_in; (void)out_size;
  const float* x  = (const float*)d_in[0];
  const float* W1 = (const float*)d_in[1];
  const float* b1 = (const float*)d_in[2];
  const float* W2 = (const float*)d_in[3];
  const float* b2 = (const float*)d_in[4];
  float* out = (float*)d_out;

  _Float16* xt  = (_Float16*)d_ws;
  _Float16* w1t = xt  + 4194304;
  _Float16* w2t = w1t + 4194304;
  unsigned* partial = (unsigned*)(w2t + 524288);   // 64 MB packed fp16
  const size_t need = (size_t)(4194304 + 4194304 + 524288)*2 + (size_t)16777216*4;
  int use_partial = (ws_size >= need) ? 1 : 0;

  hipLaunchKernelGGL(k_prep, dim3(2432), dim3(256), 0, stream, x, W1, W2, xt, w1t, w2t);
  if (!use_partial)
    hipLaunchKernelGGL(k_init_out, dim3(4096), dim3(256), 0, stream, b2, out);
  hipLaunchKernelGGL(k_treemlp, dim3(512), dim3(1024), 0, stream,
                     xt, w1t, w2t, b1, partial, out, use_partial);
  if (use_partial)
    hipLaunchKernelGGL(k_reduce, dim3(8192), dim3(256), 0, stream, partial, b2, out);
}

// Round 10
// 199.267 us; speedup vs baseline: 1.2129x; 1.0857x over previous
//
#include <hip/hip_runtime.h>
#include <hip/hip_bf16.h>

// TreeMLP fused kernel for MI355X (gfx950), round 10.
//
// pre_l = b1 + sum_{j>=l} x_blockj @ W1_blockj  -> reverse-order K-loop with
// snapshots; GEMM2 fused per snapshot. R10 vs R9 (producer/consumer kept):
//  - 768-thr blocks (12 waves, 3/EU -> 168-reg budget; R9's 128 budget left
//    VGPR=56: zero pipelining window, ~200cyc L2 latency exposed per load)
//  - 4 consumers (cell = rt), each does both tok-halves: 2 MFMA per wf,
//    w2 stream halved; K-loop in 4 chunks of 8 batched wf loads
//  - producer s-loop in 2 chunks of 4 (8 w1 frags in flight)
//  - v_cvt_pkrtz_f16_f32 for all f32->f16 packing (1 op / 2 vals)
//
// ws layout:
//   xt : fp16 [128 tg][64 kf][64 lane][8]      8 MB   (32x32 B-frag order)
//   w1t: fp16 [8 hq][64 kf][16 ht][64 lane][8] 8 MB   (32x32 A-frag order)
//   w2t: fp16 [8 hq][32 kf][4 rt][64 lane][8]  1 MB   (32x32 B-frag order)
//   partial: u32 [8 hq][64 tt][8 j][32 tc][128 r]     64 MB
// total 84,934,656 B.

typedef _Float16 half8 __attribute__((ext_vector_type(8)));
typedef _Float16 half4 __attribute__((ext_vector_type(4)));
typedef _Float16 half2v __attribute__((ext_vector_type(2)));
typedef __fp16   fp16x2 __attribute__((ext_vector_type(2)));
typedef float    f32x4  __attribute__((ext_vector_type(4)));
typedef float    f32x16 __attribute__((ext_vector_type(16)));

#define MFMA3216(A,B,C) __builtin_amdgcn_mfma_f32_32x32x16_f16(A, B, C, 0, 0, 0)

__device__ __forceinline__ float gelu_f(float x){
  // 0.5x(1+tanh(c(x+0.044715x^3))) == x * sigmoid(x*(2c + 2c*0.044715*x^2))
  // folded with log2(e) for direct exp2
  float t2 = x * fmaf(x*x, -0.10294324f, -2.30220842f);
  float e  = __builtin_amdgcn_exp2f(t2);
  return x * __builtin_amdgcn_rcpf(1.0f + e);
}

#define XROW 1028   // x-prep LDS row stride in halves (1024 + 4: 2-way free)

// ---- fused prep: cast fp32->fp16 into MFMA fragment lane order ----
__global__ void k_prep(const float* __restrict__ x, const float* __restrict__ w1,
                       const float* __restrict__ w2,
                       _Float16* __restrict__ xt, _Float16* __restrict__ w1t,
                       _Float16* __restrict__ w2t){
  __shared__ _Float16 Xs[32*XROW];                   // 65.8 KB (x-branch only)
  int bid = blockIdx.x;
  int t   = threadIdx.x;
  if (bid < 128){                                    // xt: 32x32 B-frags
    // phase 1: coalesced read of 32 tokens x 1024 cols -> padded LDS
    const float4* x4 = reinterpret_cast<const float4*>(x) + (size_t)bid*8192;
    #pragma unroll
    for (int i = 0; i < 32; ++i){
      float4 v = x4[i*256 + t];
      half4 h;
      h[0]=(_Float16)v.x; h[1]=(_Float16)v.y; h[2]=(_Float16)v.z; h[3]=(_Float16)v.w;
      *reinterpret_cast<half4*>(Xs + i*XROW + t*4) = h;
    }
    __syncthreads();
    // phase 2: emit 32x32 B-fragments (tgg = bid)
    #pragma unroll
    for (int f = 0; f < 16; ++f){
      int fragidx = f*256 + t;                       // [kf 64][lane 64]
      int lane = fragidx & 63, kf = fragidx >> 6;
      int tok32 = lane & 31;
      int k = kf*16 + (lane >> 5)*8;
      half8 v = *reinterpret_cast<const half8*>(Xs + tok32*XROW + k);
      *reinterpret_cast<half8*>(xt + ((size_t)bid*4096 + fragidx)*8) = v;
    }
  } else if (bid < 2176){                            // w1t: 32x32 A-frags
    int tid = (bid - 128)*256 + t;
    int lane = tid & 63;
    int ht   = (tid >> 6) & 15;
    int kf   = (tid >> 10) & 63;
    int hq   = tid >> 16;
    int n = hq*512 + ht*32 + (lane & 31);
    int k = kf*16 + (lane >> 5)*8;
    half8 v;
    #pragma unroll
    for (int jj = 0; jj < 8; ++jj) v[jj] = (_Float16)w1[(size_t)(k + jj)*4096 + n];
    *reinterpret_cast<half8*>(w1t + (size_t)tid*8) = v;
  } else {                                           // w2t: 32x32 B-frags
    int tid = (bid - 2176)*256 + t;                  // 65536 frag-lanes
    int lane = tid & 63;
    int rt   = (tid >> 6) & 3;
    int kf   = (tid >> 8) & 31;
    int hq   = tid >> 13;
    int n = rt*32 + (lane & 31);
    int k = hq*512 + kf*16 + (lane >> 5)*8;
    half8 v;
    #pragma unroll
    for (int jj = 0; jj < 8; ++jj) v[jj] = (_Float16)w2[(size_t)(k + jj)*128 + n];
    *reinterpret_cast<half8*>(w2t + (size_t)tid*8) = v;
  }
}

__global__ void k_init_out(const float* __restrict__ b2, float* __restrict__ out){
  int i = blockIdx.x*256 + threadIdx.x;              // 1048576 float4s
  float4 bv = reinterpret_cast<const float4*>(b2)[i & 31];
  reinterpret_cast<float4*>(out)[i] = bv;
}

// ---- reduce: out = b2 + sum over 8 H-eighth fp16 partials ----
// partial u32 layout: [hq][tt][j][tc 32][r 128]; u32 = {tok t, tok t+8} halves
// where t = (tc>>3)*16 + (tc&7).
__global__ void k_reduce(const unsigned* __restrict__ part, const float* __restrict__ b2,
                         float* __restrict__ out){
  int tid = blockIdx.x*256 + threadIdx.x;            // 0..2097151
  int r   = tid & 127;
  int tc  = (tid >> 7) & 31;
  int j   = (tid >> 12) & 7;
  int tt  = tid >> 15;
  float s0 = 0.f, s1 = 0.f;
  #pragma unroll
  for (int hq = 0; hq < 8; ++hq){
    unsigned v = __builtin_nontemporal_load(part + (size_t)hq*2097152 + tid);
    half2v h = __builtin_bit_cast(half2v, v);
    s0 += (float)h[0];
    s1 += (float)h[1];
  }
  int tka = tt*64 + (tc >> 3)*16 + (tc & 7);
  float bb = b2[r];
  out[(size_t)tka*1024 + j*128 + r]       = s0 + bb;
  out[(size_t)(tka+8)*1024 + j*128 + r]   = s1 + bb;
}

// ---- main fused kernel ----
// grid 512 x 768 thr (12 waves, 1 block/CU, 3 waves/EU -> 168-reg budget).
// block = (64 tok) x (H-8th 512).
// Producers (w 0-7): GEMM1 32x32x16 (2 hcol-tiles x 2 tok-groups, f32x16
// suffix accs) in 2 chunks of 4 k-steps (8 w1 frags in flight) + gelu
// (pkrtz) -> Pbuf[L&1]; stage x(L-1) -> Xls[(L-1)&1].
// Consumers (w 8-11): cell = rt; GEMM2 32x32x16 both tok-halves, K=512 in
// 4 chunks of 8 batched wf loads; full-line partial stores.
// ONE barrier per interval, 9 intervals.
__global__ __launch_bounds__(768, 3) void k_treemlp(
    const _Float16* __restrict__ xt, const _Float16* __restrict__ w1t,
    const _Float16* __restrict__ w2t, const float* __restrict__ b1,
    unsigned* __restrict__ partial, float* __restrict__ out, int use_partial){
  int b    = blockIdx.x;
  int hq   = b & 7;                     // H-eighth == XCD slot
  int tt   = b >> 3;                    // token tile 0..63 (64 tokens)
  int t    = threadIdx.x;
  int w    = t >> 6;                    // wave 0..11
  int lane = t & 63;
  int t32 = lane & 31, q2 = lane >> 5;

  __shared__ _Float16 Pbuf[2][32768];   // 2 x 64 KB: [th 2][kf 32][lane][8]
  __shared__ _Float16 Xls[2][8192];     // 2 x 16 KB: [tg 2][s 8][lane][8]

  // producer state: suffix accumulators (C^T: rows=hcol, cols=tok), b1-init
  f32x16 acc1[2][2];                    // [hcol-tile hf][tok-group tg]
  if (w < 8){
    #pragma unroll
    for (int hf = 0; hf < 2; ++hf){
      int base = hq*512 + (w*2 + hf)*32;
      #pragma unroll
      for (int g = 0; g < 4; ++g){
        float4 bv = *reinterpret_cast<const float4*>(b1 + base + 8*g + 4*q2);
        #pragma unroll
        for (int c = 0; c < 4; ++c){
          acc1[hf][0][g*4 + c] = ((const float*)&bv)[c];
          acc1[hf][1][g*4 + c] = ((const float*)&bv)[c];
        }
      }
    }
    // initial stage: level 7 -> Xls[1] (producers: 2 b128 each)
    #pragma unroll
    for (int c = 0; c < 2; ++c){
      int idx = c*512 + (w*64 + lane);
      int lane_s = idx & 63, s = (idx >> 6) & 7, tgl = idx >> 9;
      half8 v = *reinterpret_cast<const half8*>(
          xt + (size_t)((tt*2 + tgl)*64 + 7*8 + s)*512 + lane_s*8);
      *reinterpret_cast<half8*>(&Xls[1][(size_t)idx*8]) = v;
    }
  }
  __syncthreads();

  const _Float16* w1base = w1t + (size_t)hq*524288 + (size_t)(w*2)*512 + lane*8;
  int rt = w - 8;                       // consumer cell (R-tile of 32)
  const _Float16* w2base = w2t + ((size_t)(hq*32)*4 + rt)*512 + lane*8; // + kf*2048

  #pragma unroll
  for (int k = 0; k < 9; ++k){
    if (w < 8){
      // ================= PRODUCER =================
      if (k <= 7){
        int L = 7 - k;                   // level being produced
        // stage x(L-1) for next interval (2 b128 per producer thread)
        if (L >= 1){
          #pragma unroll
          for (int c = 0; c < 2; ++c){
            int idx = c*512 + (w*64 + lane);
            int lane_s = idx & 63, s = (idx >> 6) & 7, tgl = idx >> 9;
            half8 v = *reinterpret_cast<const half8*>(
                xt + (size_t)((tt*2 + tgl)*64 + (L-1)*8 + s)*512 + lane_s*8);
            *reinterpret_cast<half8*>(&Xls[(L-1) & 1][(size_t)idx*8]) = v;
          }
        }
        // GEMM1 level L: 2 chunks of 4 k-steps, 8 w1 frags batched in flight
        const _Float16* xb = Xls[L & 1];
        #pragma unroll
        for (int c2 = 0; c2 < 2; ++c2){
          half8 af[8];
          #pragma unroll
          for (int u = 0; u < 4; ++u){
            int kfg = L*8 + c2*4 + u;
            af[u*2    ] = *reinterpret_cast<const half8*>(w1base + (size_t)(kfg*16    )*512);
            af[u*2 + 1] = *reinterpret_cast<const half8*>(w1base + (size_t)(kfg*16 + 1)*512);
          }
          #pragma unroll
          for (int u = 0; u < 4; ++u){
            int s = c2*4 + u;
            half8 x0 = *reinterpret_cast<const half8*>(&xb[(size_t)((    s)*64 + lane)*8]);
            half8 x1 = *reinterpret_cast<const half8*>(&xb[(size_t)((8 + s)*64 + lane)*8]);
            acc1[0][0] = MFMA3216(af[u*2    ], x0, acc1[0][0]);
            acc1[0][1] = MFMA3216(af[u*2    ], x1, acc1[0][1]);
            acc1[1][0] = MFMA3216(af[u*2 + 1], x0, acc1[1][0]);
            acc1[1][1] = MFMA3216(af[u*2 + 1], x1, acc1[1][1]);
          }
        }
        // gelu (pkrtz pack) -> Pbuf[L&1] in 32x32 A-frag order
        _Float16* pb = Pbuf[L & 1];
        #pragma unroll
        for (int hf = 0; hf < 2; ++hf)
          #pragma unroll
          for (int tg = 0; tg < 2; ++tg)
            #pragma unroll
            for (int g2 = 0; g2 < 4; ++g2){
              fp16x2 lo = __builtin_amdgcn_cvt_pkrtz(
                  gelu_f(acc1[hf][tg][g2*4 + 0]), gelu_f(acc1[hf][tg][g2*4 + 1]));
              fp16x2 hi = __builtin_amdgcn_cvt_pkrtz(
                  gelu_f(acc1[hf][tg][g2*4 + 2]), gelu_f(acc1[hf][tg][g2*4 + 3]));
              half4 hv;
              hv[0]=(_Float16)lo[0]; hv[1]=(_Float16)lo[1];
              hv[2]=(_Float16)hi[0]; hv[3]=(_Float16)hi[1];
              int kf = (w*2 + hf)*2 + (g2 >> 1);
              *reinterpret_cast<half4*>(
                  &pb[(size_t)((tg*32 + kf)*64 + t32 + 32*(g2 & 1))*8 + 4*q2]) = hv;
            }
      }
    } else {
      // ================= CONSUMER =================
      if (k >= 1){
        int Lc = 8 - k;                  // level being consumed
        const _Float16* pb = Pbuf[Lc & 1];
        f32x16 o0, o1;
        #pragma unroll
        for (int c = 0; c < 16; ++c){ o0[c] = 0.f; o1[c] = 0.f; }
        #pragma unroll
        for (int c4 = 0; c4 < 4; ++c4){
          half8 wfb[8];
          #pragma unroll
          for (int u = 0; u < 8; ++u)
            wfb[u] = *reinterpret_cast<const half8*>(w2base + (size_t)(c4*8 + u)*2048);
          #pragma unroll
          for (int u = 0; u < 8; ++u){
            int kf = c4*8 + u;
            half8 p0 = *reinterpret_cast<const half8*>(&pb[(size_t)((     kf)*64 + lane)*8]);
            half8 p1 = *reinterpret_cast<const half8*>(&pb[(size_t)((32 + kf)*64 + lane)*8]);
            o0 = MFMA3216(p0, wfb[u], o0);
            o1 = MFMA3216(p1, wfb[u], o1);
          }
        }
        if (use_partial){
          // full-line stores: u32[hq][tt][j][tc][r]
          unsigned* pbase = partial + (size_t)hq*2097152 + (size_t)tt*32768
                          + (size_t)Lc*4096;
          #pragma unroll
          for (int th = 0; th < 2; ++th){
            const f32x16& oJ = th ? o1 : o0;
            #pragma unroll
            for (int i = 0; i < 8; ++i){
              int gg = i >> 2, ii = i & 3;
              int lo = gg*8 + ii;
              fp16x2 p = __builtin_amdgcn_cvt_pkrtz(oJ[lo], oJ[lo + 4]);
              int tc = (th*2 + gg)*8 + ii + 4*q2;
              __builtin_nontemporal_store(__builtin_bit_cast(unsigned, p),
                                          pbase + (size_t)tc*128 + rt*32 + t32);
            }
          }
        } else {
          #pragma unroll
          for (int th = 0; th < 2; ++th){
            const f32x16& oJ = th ? o1 : o0;
            #pragma unroll
            for (int reg = 0; reg < 16; ++reg){
              int tok = tt*64 + th*32 + (reg & 3) + 8*(reg >> 2) + 4*q2;
              atomicAdd(out + (size_t)tok*1024 + Lc*128 + rt*32 + t32, oJ[reg]);
            }
          }
        }
      }
    }
    __syncthreads();
  }
}

extern "C" void kernel_launch(void* const* d_in, const int* in_sizes, int n_in,
                              void* d_out, int out_size, void* d_ws, size_t ws_size,
                              hipStream_t stream){
  (void)in_sizes; (void)n_in; (void)out_size;
  const float* x  = (const float*)d_in[0];
  const float* W1 = (const float*)d_in[1];
  const float* b1 = (const float*)d_in[2];
  const float* W2 = (const float*)d_in[3];
  const float* b2 = (const float*)d_in[4];
  float* out = (float*)d_out;

  _Float16* xt  = (_Float16*)d_ws;
  _Float16* w1t = xt  + 4194304;
  _Float16* w2t = w1t + 4194304;
  unsigned* partial = (unsigned*)(w2t + 524288);   // 64 MB packed fp16
  const size_t need = (size_t)(4194304 + 4194304 + 524288)*2 + (size_t)16777216*4;
  int use_partial = (ws_size >= need) ? 1 : 0;

  hipLaunchKernelGGL(k_prep, dim3(2432), dim3(256), 0, stream, x, W1, W2, xt, w1t, w2t);
  if (!use_partial)
    hipLaunchKernelGGL(k_init_out, dim3(4096), dim3(256), 0, stream, b2, out);
  hipLaunchKernelGGL(k_treemlp, dim3(512), dim3(768), 0, stream,
                     xt, w1t, w2t, b1, partial, out, use_partial);
  if (use_partial)
    hipLaunchKernelGGL(k_reduce, dim3(8192), dim3(256), 0, stream, partial, b2, out);
}